// Round 8
// baseline (577.767 us; speedup 1.0000x reference)
//
#include <hip/hip_runtime.h>

#define D_MODEL 2048
#define D_LATENT 512
#define NUM_HEADS 16
#define D_HEAD 128
#define BATCH 4
#define SEQ 2048
#define MTOK (BATCH*SEQ)   // 8192 tokens

typedef __bf16 bf16_t;
typedef __bf16 bf16x4 __attribute__((ext_vector_type(4)));
typedef __bf16 bf16x8 __attribute__((ext_vector_type(8)));
typedef float  f32x4  __attribute__((ext_vector_type(4)));

// async global->LDS, 16B per lane; LDS dst = wave-uniform base + lane*16 (m97 contract)
__device__ __forceinline__ void load_lds16(const bf16_t* g, bf16_t* l) {
  __builtin_amdgcn_global_load_lds(
      (const __attribute__((address_space(1))) void*)g,
      (__attribute__((address_space(3))) void*)l,
      16, 0, 0);
}

// ---------------- fp32 -> bf16 elementwise convert (separate kernel: R7's
// fusion into transpose_w_all cost +20us from lost TLP; R6 structure restored)
__global__ void convert_f32_bf16_kernel(const float* __restrict__ src,
                                        bf16_t* __restrict__ dst, int n4) {
  int i = blockIdx.x * 256 + threadIdx.x;
  if (i >= n4) return;
  float4 v = *(const float4*)&src[(size_t)i * 4];
  bf16x4 o = { (bf16_t)v.x, (bf16_t)v.y, (bf16_t)v.z, (bf16_t)v.w };
  *(bf16x4*)&dst[(size_t)i * 4] = o;
}

// ------- merged weight transposes: 5 matrices, one launch (z-indexed) -------
__global__ void transpose_w_all(const float* __restrict__ a0, const float* __restrict__ a1,
                                const float* __restrict__ a2, const float* __restrict__ a3,
                                const float* __restrict__ a4,
                                bf16_t* __restrict__ o0, bf16_t* __restrict__ o1,
                                bf16_t* __restrict__ o2, bf16_t* __restrict__ o3,
                                bf16_t* __restrict__ o4) {
  __shared__ __align__(16) bf16_t tile[64][66];
  int z = blockIdx.z;
  const float* src; bf16_t* dst; int R, C;
  switch (z) {
    case 0: src = a0; dst = o0; R = D_MODEL; C = D_LATENT; break;   // W_down
    case 1: src = a1; dst = o1; R = D_LATENT; C = D_MODEL; break;   // W_uk
    case 2: src = a2; dst = o2; R = D_LATENT; C = D_MODEL; break;   // W_uv
    case 3: src = a3; dst = o3; R = D_MODEL; C = D_MODEL; break;    // W_q
    default: src = a4; dst = o4; R = D_MODEL; C = D_MODEL; break;   // W_o
  }
  if ((int)blockIdx.x * 64 >= C || (int)blockIdx.y * 64 >= R) return;
  int rt = blockIdx.y * 64, ct = blockIdx.x * 64;
  int lc = threadIdx.x & 63, lr = threadIdx.x >> 6;
  for (int i = 0; i < 64; i += 4)
    tile[lr + i][lc] = (bf16_t)src[(size_t)(rt + lr + i) * C + ct + lc];
  __syncthreads();
  for (int i = 0; i < 64; i += 4)
    dst[(size_t)(ct + lr + i) * R + rt + lc] = tile[lc][lr + i];
}

// ---------------- GEMM core macro-body (m97 structure, measured-good) ----------------
// 128x128 tile, 4 waves, BK=32, global_load_lds width-16 staging.

// generic: C[M][N] = (A @ Wt^T + bias) * premul  (used for the o-projection)
template<typename OutT>
__global__ __launch_bounds__(256, 2) void gemm_bt_kernel(
    const bf16_t* __restrict__ A, const bf16_t* __restrict__ Wt,
    const float* __restrict__ bias, OutT* __restrict__ C,
    int M, int N, int K, float premul)
{
  __shared__ __align__(16) bf16_t As[128 * 32];
  __shared__ __align__(16) bf16_t Bs[128 * 32];
  int tid = threadIdx.x;
  int lane = tid & 63, wave = tid >> 6;
  int wr = (wave >> 1) * 64, wc = (wave & 1) * 64;
  size_t row0 = (size_t)blockIdx.x * 128, col0 = (size_t)blockIdx.y * 128;
  int lr = lane & 15, quad = lane >> 4, rq = quad * 4;

  f32x4 acc[4][4] = {};

  int srow = wave * 32 + (lane >> 2);
  int scol = ((lane & 3) ^ ((lane >> 3) & 3)) * 8;
  const bf16_t* Ag = A  + (row0 + srow) * K + scol;
  const bf16_t* Bg = Wt + (col0 + srow) * K + scol;
  bf16_t* Asw = As + wave * 1024;
  bf16_t* Bsw = Bs + wave * 1024;

  int rchunk = (quad ^ ((lr >> 1) & 3)) * 8;

  for (int k0 = 0; k0 < K; k0 += 32) {
    __syncthreads();
    load_lds16(Ag,          Asw);
    load_lds16(Ag + 16 * K, Asw + 512);
    load_lds16(Bg,          Bsw);
    load_lds16(Bg + 16 * K, Bsw + 512);
    Ag += 32; Bg += 32;
    __syncthreads();

    bf16x8 af[4], bfr[4];
    #pragma unroll
    for (int mi = 0; mi < 4; ++mi)
      af[mi] = *(const bf16x8*)&As[(wr + mi * 16 + lr) * 32 + rchunk];
    #pragma unroll
    for (int ni = 0; ni < 4; ++ni)
      bfr[ni] = *(const bf16x8*)&Bs[(wc + ni * 16 + lr) * 32 + rchunk];
    #pragma unroll
    for (int mi = 0; mi < 4; ++mi)
      #pragma unroll
      for (int ni = 0; ni < 4; ++ni)
        acc[mi][ni] = __builtin_amdgcn_mfma_f32_16x16x32_bf16(af[mi], bfr[ni], acc[mi][ni], 0, 0, 0);
  }

  #pragma unroll
  for (int ni = 0; ni < 4; ++ni) {
    int col = (int)col0 + wc + ni * 16 + lr;
    float bv = bias[col];
    #pragma unroll
    for (int mi = 0; mi < 4; ++mi) {
      #pragma unroll
      for (int r = 0; r < 4; ++r) {
        size_t row = row0 + wr + mi * 16 + rq + r;
        C[row * N + col] = (OutT)((acc[mi][ni][r] + bv) * premul);
      }
    }
  }
}

// fused down+q GEMM: both read xb (K=2048). blockIdx.y<4 -> lat (N=512, premul 1);
// y>=4 -> qm (N=2048, premul cs). One launch instead of two.
__global__ __launch_bounds__(256, 2) void gemm_dq_kernel(
    const bf16_t* __restrict__ A, const bf16_t* __restrict__ WtD,
    const bf16_t* __restrict__ WtQ, const float* __restrict__ biasD,
    const float* __restrict__ biasQ, bf16_t* __restrict__ CD,
    bf16_t* __restrict__ CQ, int M, float premulQ)
{
  const int K = D_MODEL;
  __shared__ __align__(16) bf16_t As[128 * 32];
  __shared__ __align__(16) bf16_t Bs[128 * 32];
  int tid = threadIdx.x;
  int lane = tid & 63, wave = tid >> 6;
  int wr = (wave >> 1) * 64, wc = (wave & 1) * 64;
  int yb = blockIdx.y;
  bool isq = yb >= 4;
  const bf16_t* Wt = isq ? WtQ : WtD;
  const float* bias = isq ? biasQ : biasD;
  bf16_t* C = isq ? CQ : CD;
  int N = isq ? D_MODEL : D_LATENT;
  float premul = isq ? premulQ : 1.0f;
  size_t row0 = (size_t)blockIdx.x * 128, col0 = (size_t)(isq ? yb - 4 : yb) * 128;
  int lr = lane & 15, quad = lane >> 4, rq = quad * 4;

  f32x4 acc[4][4] = {};

  int srow = wave * 32 + (lane >> 2);
  int scol = ((lane & 3) ^ ((lane >> 3) & 3)) * 8;
  const bf16_t* Ag = A  + (row0 + srow) * K + scol;
  const bf16_t* Bg = Wt + (col0 + srow) * K + scol;
  bf16_t* Asw = As + wave * 1024;
  bf16_t* Bsw = Bs + wave * 1024;

  int rchunk = (quad ^ ((lr >> 1) & 3)) * 8;

  for (int k0 = 0; k0 < K; k0 += 32) {
    __syncthreads();
    load_lds16(Ag,          Asw);
    load_lds16(Ag + 16 * K, Asw + 512);
    load_lds16(Bg,          Bsw);
    load_lds16(Bg + 16 * K, Bsw + 512);
    Ag += 32; Bg += 32;
    __syncthreads();

    bf16x8 af[4], bfr[4];
    #pragma unroll
    for (int mi = 0; mi < 4; ++mi)
      af[mi] = *(const bf16x8*)&As[(wr + mi * 16 + lr) * 32 + rchunk];
    #pragma unroll
    for (int ni = 0; ni < 4; ++ni)
      bfr[ni] = *(const bf16x8*)&Bs[(wc + ni * 16 + lr) * 32 + rchunk];
    #pragma unroll
    for (int mi = 0; mi < 4; ++mi)
      #pragma unroll
      for (int ni = 0; ni < 4; ++ni)
        acc[mi][ni] = __builtin_amdgcn_mfma_f32_16x16x32_bf16(af[mi], bfr[ni], acc[mi][ni], 0, 0, 0);
  }

  #pragma unroll
  for (int ni = 0; ni < 4; ++ni) {
    int col = (int)col0 + wc + ni * 16 + lr;
    float bv = bias[col];
    #pragma unroll
    for (int mi = 0; mi < 4; ++mi) {
      #pragma unroll
      for (int r = 0; r < 4; ++r) {
        size_t row = row0 + wr + mi * 16 + rq + r;
        C[row * N + col] = (bf16_t)((acc[mi][ni][r] + bv) * premul);
      }
    }
  }
}

// fused uk+uv GEMM (A=lat, K=512). blockIdx.y<16 -> keys; y>=16 -> uv with
// transposing epilogue writing vt[bh][d][s] directly (R6-verified).
__global__ __launch_bounds__(256, 2) void gemm_kv_kernel(
    const bf16_t* __restrict__ A, const bf16_t* __restrict__ WtK,
    const bf16_t* __restrict__ WtV, const float* __restrict__ biasK,
    const float* __restrict__ biasV, bf16_t* __restrict__ keysO,
    bf16_t* __restrict__ vtO, int M)
{
  const int K = D_LATENT;
  __shared__ __align__(16) bf16_t As[128 * 32];
  __shared__ __align__(16) bf16_t Bs[128 * 32];
  __shared__ __align__(16) bf16_t E[64 * 136];
  int tid = threadIdx.x;
  int lane = tid & 63, wave = tid >> 6;
  int wr = (wave >> 1) * 64, wc = (wave & 1) * 64;
  int yb = blockIdx.y;
  bool isv = yb >= 16;
  const bf16_t* Wt = isv ? WtV : WtK;
  const float* bias = isv ? biasV : biasK;
  size_t row0 = (size_t)blockIdx.x * 128, col0 = (size_t)(isv ? yb - 16 : yb) * 128;
  int lr = lane & 15, quad = lane >> 4, rq = quad * 4;

  f32x4 acc[4][4] = {};

  int srow = wave * 32 + (lane >> 2);
  int scol = ((lane & 3) ^ ((lane >> 3) & 3)) * 8;
  const bf16_t* Ag = A  + (row0 + srow) * K + scol;
  const bf16_t* Bg = Wt + (col0 + srow) * K + scol;
  bf16_t* Asw = As + wave * 1024;
  bf16_t* Bsw = Bs + wave * 1024;

  int rchunk = (quad ^ ((lr >> 1) & 3)) * 8;

  for (int k0 = 0; k0 < K; k0 += 32) {
    __syncthreads();
    load_lds16(Ag,          Asw);
    load_lds16(Ag + 16 * K, Asw + 512);
    load_lds16(Bg,          Bsw);
    load_lds16(Bg + 16 * K, Bsw + 512);
    Ag += 32; Bg += 32;
    __syncthreads();

    bf16x8 af[4], bfr[4];
    #pragma unroll
    for (int mi = 0; mi < 4; ++mi)
      af[mi] = *(const bf16x8*)&As[(wr + mi * 16 + lr) * 32 + rchunk];
    #pragma unroll
    for (int ni = 0; ni < 4; ++ni)
      bfr[ni] = *(const bf16x8*)&Bs[(wc + ni * 16 + lr) * 32 + rchunk];
    #pragma unroll
    for (int mi = 0; mi < 4; ++mi)
      #pragma unroll
      for (int ni = 0; ni < 4; ++ni)
        acc[mi][ni] = __builtin_amdgcn_mfma_f32_16x16x32_bf16(af[mi], bfr[ni], acc[mi][ni], 0, 0, 0);
  }

  if (!isv) {
    #pragma unroll
    for (int ni = 0; ni < 4; ++ni) {
      int col = (int)col0 + wc + ni * 16 + lr;
      float bv = bias[col];
      #pragma unroll
      for (int mi = 0; mi < 4; ++mi) {
        #pragma unroll
        for (int r = 0; r < 4; ++r) {
          size_t row = row0 + wr + mi * 16 + rq + r;
          keysO[row * D_MODEL + col] = (bf16_t)(acc[mi][ni][r] + bv);
        }
      }
    }
  } else {
    int b = (int)(row0 >> 11);
    int s0 = (int)(row0 & 2047);
    int h = yb - 16;
    bf16_t* vtb = vtO + (size_t)(b * NUM_HEADS + h) * D_HEAD * SEQ;
    #pragma unroll
    for (int h2 = 0; h2 < 2; ++h2) {
      __syncthreads();
      if ((wave & 1) == h2) {
        #pragma unroll
        for (int ni = 0; ni < 4; ++ni) {
          int dh = ni * 16 + lr;
          float bv = bias[(int)col0 + h2 * 64 + dh];
          #pragma unroll
          for (int mi = 0; mi < 4; ++mi) {
            #pragma unroll
            for (int r = 0; r < 4; ++r) {
              int s = wr + mi * 16 + rq + r;
              E[dh * 136 + s] = (bf16_t)(acc[mi][ni][r] + bv);
            }
          }
        }
      }
      __syncthreads();
      for (int t = tid; t < 1024; t += 256) {
        int d = t >> 4, ch = t & 15;
        bf16x8 v = *(const bf16x8*)&E[d * 136 + ch * 8];
        *(bf16x8*)&vtb[(size_t)(h2 * 64 + d) * SEQ + s0 + ch * 8] = v;
      }
    }
  }
}

// ---------------- flash attention (R7-verified: unroll x2, precomputed
// swizzled offsets, zero-C MFMA init; 198.5us measured) ----------------
__global__ __launch_bounds__(256, 2) void attention_kernel(
    const bf16_t* __restrict__ q, const bf16_t* __restrict__ keys,
    const bf16_t* __restrict__ vt, bf16_t* __restrict__ ctx)
{
  __shared__ __align__(16) bf16_t KS[2][64 * 128];   // 32KB  [key][d] swizzled
  __shared__ __align__(16) bf16_t VS[2][128 * 64];   // 32KB  [d][key] swizzled
  __shared__ __align__(16) bf16_t PS[128 * 64];      // 16KB  [q][key] swizzled
  int wg = blockIdx.x;
  int qt = (wg >> 3) & 15;
  int bh = (wg & 7) | ((wg >> 7) << 3);
  int b = bh >> 4, h = bh & 15;
  int tid = threadIdx.x, lane = tid & 63, wave = tid >> 6;
  int lr = lane & 15, quad = lane >> 4, kq = quad * 8, rq = quad * 4;
  int l7 = lr & 7;

  const bf16_t* qg = q    + (size_t)(b * SEQ + qt * 128) * D_MODEL + h * D_HEAD;
  const bf16_t* kg = keys + (size_t)b * SEQ * D_MODEL + h * D_HEAD;
  const bf16_t* vg = vt   + (size_t)bh * D_HEAD * SEQ;

  // Q fragments (B operand; layout: n=lane&15, k=quad*8+j)
  bf16x8 qf[2][4];
  #pragma unroll
  for (int mi = 0; mi < 2; ++mi)
    #pragma unroll
    for (int ks = 0; ks < 4; ++ks)
      qf[mi][ks] = *(const bf16x8*)&qg[(size_t)(wave*32 + mi*16 + lr) * D_MODEL + ks*32 + kq];

  // precomputed swizzled LDS offsets (loop-invariant; frag idx -> immediates)
  int koff[4], voff2[2], poff2[2], pwaddr[4];
  #pragma unroll
  for (int ks = 0; ks < 4; ++ks)
    koff[ks] = lr * 128 + (((ks*4 + quad) ^ l7) * 8);          // + ni*2048 imm
  #pragma unroll
  for (int ks2 = 0; ks2 < 2; ++ks2) {
    voff2[ks2] = lr * 64 + (((ks2*4 + quad) ^ l7) * 8);        // + nd*1024 imm
    poff2[ks2] = (wave*32 + lr) * 64 + (((ks2*4 + quad) ^ l7) * 8);  // + mi*1024 imm
  }
  #pragma unroll
  for (int ni = 0; ni < 4; ++ni)                               // P-write, + mi*1024 imm
    pwaddr[ni] = (wave*32 + lr) * 64 + (((ni*2 + (quad>>1)) ^ l7) * 8) + (quad&1)*4;

  // staging coords (LDS offsets pre-swizzled) + prefetch registers
  bf16x8 kreg[4], vreg[4];
  const bf16_t* kp4[4];
  const bf16_t* vp4[4];
  int kdo[4], vdo[4];
  #pragma unroll
  for (int i = 0; i < 4; ++i) {
    int c = tid + i * 256;
    int r = c >> 4, kc = c & 15;
    kp4[i] = kg + (size_t)r * D_MODEL + kc * 8;
    kdo[i] = r * 128 + ((kc ^ (r & 7)) * 8);
    int d = c >> 3, vc = c & 7;
    vp4[i] = vg + (size_t)d * SEQ + vc * 8;
    vdo[i] = d * 64 + ((vc ^ (d & 7)) * 8);
  }

  // prologue: tile 0 -> buf0 directly; then prefetch tile 1 into regs
  #pragma unroll
  for (int i = 0; i < 4; ++i) {
    kreg[i] = *(const bf16x8*)kp4[i];
    vreg[i] = *(const bf16x8*)vp4[i];
  }
  #pragma unroll
  for (int i = 0; i < 4; ++i) {
    *(bf16x8*)&KS[0][kdo[i]] = kreg[i];
    *(bf16x8*)&VS[0][vdo[i]] = vreg[i];
  }
  #pragma unroll
  for (int i = 0; i < 4; ++i) {
    kp4[i] += 64 * D_MODEL;
    vp4[i] += 64;
    kreg[i] = *(const bf16x8*)kp4[i];
    vreg[i] = *(const bf16x8*)vp4[i];
  }

  f32x4 accO[2][8] = {};
  float m2[2]   = {-1e30f, -1e30f};
  float lsum[2] = {0.f, 0.f};
  const f32x4 z4 = {0.f, 0.f, 0.f, 0.f};

  __syncthreads();

  // body for one K/V tile; p = compile-time buffer parity after inlining
  auto body = [&](int p, int kt) {
    // S^T = K @ Q^T : sc[mi][ni][r] at key=ni*16+rq+r, q=wave*32+mi*16+lr
    f32x4 sc[2][4];
    {
      bf16x8 kf[4];
      #pragma unroll
      for (int ni = 0; ni < 4; ++ni)
        kf[ni] = *(const bf16x8*)&KS[p][koff[0] + ni*2048];
      __builtin_amdgcn_s_setprio(1);
      #pragma unroll
      for (int mi = 0; mi < 2; ++mi)
        #pragma unroll
        for (int ni = 0; ni < 4; ++ni)
          sc[mi][ni] = __builtin_amdgcn_mfma_f32_16x16x32_bf16(kf[ni], qf[mi][0], z4, 0, 0, 0);
      __builtin_amdgcn_s_setprio(0);
    }
    #pragma unroll
    for (int ks = 1; ks < 4; ++ks) {
      bf16x8 kf[4];
      #pragma unroll
      for (int ni = 0; ni < 4; ++ni)
        kf[ni] = *(const bf16x8*)&KS[p][koff[ks] + ni*2048];
      __builtin_amdgcn_s_setprio(1);
      #pragma unroll
      for (int mi = 0; mi < 2; ++mi)
        #pragma unroll
        for (int ni = 0; ni < 4; ++ni)
          sc[mi][ni] = __builtin_amdgcn_mfma_f32_16x16x32_bf16(kf[ni], qf[mi][ks], sc[mi][ni], 0, 0, 0);
      __builtin_amdgcn_s_setprio(0);
    }

    // stage tile kt+1 into the other buffer (regs loaded last iteration)
    if (kt + 1 < SEQ/64) {
      #pragma unroll
      for (int i = 0; i < 4; ++i) {
        *(bf16x8*)&KS[p ^ 1][kdo[i]] = kreg[i];
        *(bf16x8*)&VS[p ^ 1][vdo[i]] = vreg[i];
      }
    }
    // issue global loads for tile kt+2 (depth-2 prefetch)
    if (kt + 2 < SEQ/64) {
      #pragma unroll
      for (int i = 0; i < 4; ++i) {
        kp4[i] += 64 * D_MODEL;
        vp4[i] += 64;
        kreg[i] = *(const bf16x8*)kp4[i];
        vreg[i] = *(const bf16x8*)vp4[i];
      }
    }

    // online softmax (log2 domain; scores pre-scaled by cs in the q-GEMM)
    #pragma unroll
    for (int mi = 0; mi < 2; ++mi) {
      float rm = sc[mi][0][0];
      #pragma unroll
      for (int ni = 0; ni < 4; ++ni)
        #pragma unroll
        for (int r = 0; r < 4; ++r) rm = fmaxf(rm, sc[mi][ni][r]);
      rm = fmaxf(rm, __shfl_xor(rm, 16, 64));
      rm = fmaxf(rm, __shfl_xor(rm, 32, 64));

      if (!__all(rm - m2[mi] <= 8.0f)) {        // T13 defer-max
        float mnew  = fmaxf(m2[mi], rm);
        float alpha = exp2f(m2[mi] - mnew);
        m2[mi] = mnew;
        lsum[mi] *= alpha;
        float ar[4];
        #pragma unroll
        for (int r = 0; r < 4; ++r) ar[r] = __shfl(alpha, rq + r, 16);
        #pragma unroll
        for (int nd = 0; nd < 8; ++nd)
          #pragma unroll
          for (int r = 0; r < 4; ++r) accO[mi][nd][r] *= ar[r];
      }

      float rs = 0.f;
      #pragma unroll
      for (int ni = 0; ni < 4; ++ni) {
        float p0 = exp2f(sc[mi][ni][0] - m2[mi]);
        float p1 = exp2f(sc[mi][ni][1] - m2[mi]);
        float p2 = exp2f(sc[mi][ni][2] - m2[mi]);
        float p3 = exp2f(sc[mi][ni][3] - m2[mi]);
        rs += (p0 + p1) + (p2 + p3);
        bf16x4 pk = { (bf16_t)p0, (bf16_t)p1, (bf16_t)p2, (bf16_t)p3 };
        if (mi == 0) *(bf16x4*)&PS[pwaddr[ni]]        = pk;
        else         *(bf16x4*)&PS[pwaddr[ni] + 1024] = pk;
      }
      rs += __shfl_xor(rs, 16, 64);
      rs += __shfl_xor(rs, 32, 64);
      lsum[mi] += rs;
    }

    // O += P @ V  (P rows wave-local, no barrier)
    #pragma unroll
    for (int ks2 = 0; ks2 < 2; ++ks2) {
      bf16x8 pf[2], vf[8];
      #pragma unroll
      for (int mi = 0; mi < 2; ++mi)
        pf[mi] = *(const bf16x8*)&PS[poff2[ks2] + mi*1024];
      #pragma unroll
      for (int nd = 0; nd < 8; ++nd)
        vf[nd] = *(const bf16x8*)&VS[p][voff2[ks2] + nd*1024];
      __builtin_amdgcn_s_setprio(1);
      #pragma unroll
      for (int mi = 0; mi < 2; ++mi)
        #pragma unroll
        for (int nd = 0; nd < 8; ++nd)
          accO[mi][nd] = __builtin_amdgcn_mfma_f32_16x16x32_bf16(pf[mi], vf[nd], accO[mi][nd], 0, 0, 0);
      __builtin_amdgcn_s_setprio(0);
    }

    __syncthreads();   // single barrier per tile
  };

  for (int kt = 0; kt < SEQ/64; kt += 2) {
    body(0, kt);
    body(1, kt + 1);
  }

  bf16_t* og = ctx + (size_t)(b * SEQ + qt * 128) * D_MODEL + h * D_HEAD;
  #pragma unroll
  for (int mi = 0; mi < 2; ++mi) {
    float inv[4];
    #pragma unroll
    for (int r = 0; r < 4; ++r) inv[r] = 1.0f / __shfl(lsum[mi], rq + r, 16);
    #pragma unroll
    for (int r = 0; r < 4; ++r) {
      int row = wave*32 + mi*16 + rq + r;
      #pragma unroll
      for (int nd = 0; nd < 8; ++nd)
        og[(size_t)row * D_MODEL + nd*16 + lr] = (bf16_t)(accO[mi][nd][r] * inv[r]);
    }
  }
}

extern "C" void kernel_launch(void* const* d_in, const int* in_sizes, int n_in,
                              void* d_out, int out_size, void* d_ws, size_t ws_size,
                              hipStream_t stream) {
  const float* x      = (const float*)d_in[0];
  const float* W_down = (const float*)d_in[1];
  const float* b_down = (const float*)d_in[2];
  const float* W_uk   = (const float*)d_in[3];
  const float* b_uk   = (const float*)d_in[4];
  const float* W_uv   = (const float*)d_in[5];
  const float* b_uv   = (const float*)d_in[6];
  const float* W_q    = (const float*)d_in[7];
  const float* b_q    = (const float*)d_in[8];
  const float* W_o    = (const float*)d_in[9];
  const float* b_o    = (const float*)d_in[10];
  float* out = (float*)d_out;

  char* ws = (char*)d_ws;
  bf16_t* xb      = (bf16_t*)ws;  ws += (size_t)MTOK*D_MODEL*2;
  bf16_t* Wt_down = (bf16_t*)ws;  ws += (size_t)D_LATENT*D_MODEL*2;
  bf16_t* Wt_uk   = (bf16_t*)ws;  ws += (size_t)D_MODEL*D_LATENT*2;
  bf16_t* Wt_uv   = (bf16_t*)ws;  ws += (size_t)D_MODEL*D_LATENT*2;
  bf16_t* Wt_q    = (bf16_t*)ws;  ws += (size_t)D_MODEL*D_MODEL*2;
  bf16_t* Wt_o    = (bf16_t*)ws;  ws += (size_t)D_MODEL*D_MODEL*2;
  bf16_t* lat     = (bf16_t*)ws;  ws += (size_t)MTOK*D_LATENT*2;
  bf16_t* keys    = (bf16_t*)ws;  ws += (size_t)MTOK*D_MODEL*2;
  bf16_t* vals    = (bf16_t*)ws;  ws += (size_t)MTOK*D_MODEL*2;  // ctx only
  bf16_t* qm      = (bf16_t*)ws;  ws += (size_t)MTOK*D_MODEL*2;
  bf16_t* vtm     = (bf16_t*)ws;  ws += (size_t)MTOK*D_MODEL*2;
  bf16_t* ctx     = vals;

  const float cs = 0.0883883476483184f * 1.44269504089f;  // 1/sqrt(128) * log2(e)

  convert_f32_bf16_kernel<<<(MTOK*D_MODEL/4 + 255)/256, 256, 0, stream>>>(x, xb, MTOK*D_MODEL/4);

  transpose_w_all<<<dim3(32, 32, 5), 256, 0, stream>>>(
      W_down, W_uk, W_uv, W_q, W_o, Wt_down, Wt_uk, Wt_uv, Wt_q, Wt_o);

  gemm_dq_kernel<<<dim3(MTOK/128, 4 + D_MODEL/128), 256, 0, stream>>>(
      xb, Wt_down, Wt_q, b_down, b_q, lat, qm, MTOK, cs);

  gemm_kv_kernel<<<dim3(MTOK/128, 32), 256, 0, stream>>>(
      lat, Wt_uk, Wt_uv, b_uk, b_uv, keys, vtm, MTOK);

  attention_kernel<<<1024, 256, 0, stream>>>(qm, keys, vtm, ctx);

  gemm_bt_kernel<float><<<dim3(MTOK/128, D_MODEL/128), 256, 0, stream>>>(ctx, Wt_o, b_o, out, MTOK, D_MODEL, D_MODEL, 1.0f);
}

// Round 9
// 564.985 us; speedup vs baseline: 1.0226x; 1.0226x over previous
//
#include <hip/hip_runtime.h>

#define D_MODEL 2048
#define D_LATENT 512
#define NUM_HEADS 16
#define D_HEAD 128
#define BATCH 4
#define SEQ 2048
#define MTOK (BATCH*SEQ)   // 8192 tokens

typedef __bf16 bf16_t;
typedef __bf16 bf16x4 __attribute__((ext_vector_type(4)));
typedef __bf16 bf16x8 __attribute__((ext_vector_type(8)));
typedef float  f32x4  __attribute__((ext_vector_type(4)));

// async global->LDS, 16B per lane; LDS dst = wave-uniform base + lane*16 (m97 contract)
__device__ __forceinline__ void load_lds16(const bf16_t* g, bf16_t* l) {
  __builtin_amdgcn_global_load_lds(
      (const __attribute__((address_space(1))) void*)g,
      (__attribute__((address_space(3))) void*)l,
      16, 0, 0);
}

// ---------------- fp32 -> bf16 elementwise convert ----------------
__global__ void convert_f32_bf16_kernel(const float* __restrict__ src,
                                        bf16_t* __restrict__ dst, int n4) {
  int i = blockIdx.x * 256 + threadIdx.x;
  if (i >= n4) return;
  float4 v = *(const float4*)&src[(size_t)i * 4];
  bf16x4 o = { (bf16_t)v.x, (bf16_t)v.y, (bf16_t)v.z, (bf16_t)v.w };
  *(bf16x4*)&dst[(size_t)i * 4] = o;
}

// ------- merged weight transposes: 5 matrices, one launch (z-indexed) -------
__global__ void transpose_w_all(const float* __restrict__ a0, const float* __restrict__ a1,
                                const float* __restrict__ a2, const float* __restrict__ a3,
                                const float* __restrict__ a4,
                                bf16_t* __restrict__ o0, bf16_t* __restrict__ o1,
                                bf16_t* __restrict__ o2, bf16_t* __restrict__ o3,
                                bf16_t* __restrict__ o4) {
  __shared__ __align__(16) bf16_t tile[64][66];
  int z = blockIdx.z;
  const float* src; bf16_t* dst; int R, C;
  switch (z) {
    case 0: src = a0; dst = o0; R = D_MODEL; C = D_LATENT; break;   // W_down
    case 1: src = a1; dst = o1; R = D_LATENT; C = D_MODEL; break;   // W_uk
    case 2: src = a2; dst = o2; R = D_LATENT; C = D_MODEL; break;   // W_uv
    case 3: src = a3; dst = o3; R = D_MODEL; C = D_MODEL; break;    // W_q
    default: src = a4; dst = o4; R = D_MODEL; C = D_MODEL; break;   // W_o
  }
  if ((int)blockIdx.x * 64 >= C || (int)blockIdx.y * 64 >= R) return;
  int rt = blockIdx.y * 64, ct = blockIdx.x * 64;
  int lc = threadIdx.x & 63, lr = threadIdx.x >> 6;
  for (int i = 0; i < 64; i += 4)
    tile[lr + i][lc] = (bf16_t)src[(size_t)(rt + lr + i) * C + ct + lc];
  __syncthreads();
  for (int i = 0; i < 64; i += 4)
    dst[(size_t)(ct + lr + i) * R + rt + lc] = tile[lc][lr + i];
}

// ---------------- GEMM 128^2 (m97 structure, measured-good) ----------------
template<typename OutT>
__global__ __launch_bounds__(256, 2) void gemm_bt_kernel(
    const bf16_t* __restrict__ A, const bf16_t* __restrict__ Wt,
    const float* __restrict__ bias, OutT* __restrict__ C,
    int M, int N, int K, float premul)
{
  __shared__ __align__(16) bf16_t As[128 * 32];
  __shared__ __align__(16) bf16_t Bs[128 * 32];
  int tid = threadIdx.x;
  int lane = tid & 63, wave = tid >> 6;
  int wr = (wave >> 1) * 64, wc = (wave & 1) * 64;
  size_t row0 = (size_t)blockIdx.x * 128, col0 = (size_t)blockIdx.y * 128;
  int lr = lane & 15, quad = lane >> 4, rq = quad * 4;

  f32x4 acc[4][4] = {};

  int srow = wave * 32 + (lane >> 2);
  int scol = ((lane & 3) ^ ((lane >> 3) & 3)) * 8;
  const bf16_t* Ag = A  + (row0 + srow) * K + scol;
  const bf16_t* Bg = Wt + (col0 + srow) * K + scol;
  bf16_t* Asw = As + wave * 1024;
  bf16_t* Bsw = Bs + wave * 1024;

  int rchunk = (quad ^ ((lr >> 1) & 3)) * 8;

  for (int k0 = 0; k0 < K; k0 += 32) {
    __syncthreads();
    load_lds16(Ag,          Asw);
    load_lds16(Ag + 16 * K, Asw + 512);
    load_lds16(Bg,          Bsw);
    load_lds16(Bg + 16 * K, Bsw + 512);
    Ag += 32; Bg += 32;
    __syncthreads();

    bf16x8 af[4], bfr[4];
    #pragma unroll
    for (int mi = 0; mi < 4; ++mi)
      af[mi] = *(const bf16x8*)&As[(wr + mi * 16 + lr) * 32 + rchunk];
    #pragma unroll
    for (int ni = 0; ni < 4; ++ni)
      bfr[ni] = *(const bf16x8*)&Bs[(wc + ni * 16 + lr) * 32 + rchunk];
    #pragma unroll
    for (int mi = 0; mi < 4; ++mi)
      #pragma unroll
      for (int ni = 0; ni < 4; ++ni)
        acc[mi][ni] = __builtin_amdgcn_mfma_f32_16x16x32_bf16(af[mi], bfr[ni], acc[mi][ni], 0, 0, 0);
  }

  #pragma unroll
  for (int ni = 0; ni < 4; ++ni) {
    int col = (int)col0 + wc + ni * 16 + lr;
    float bv = bias[col];
    #pragma unroll
    for (int mi = 0; mi < 4; ++mi) {
      #pragma unroll
      for (int r = 0; r < 4; ++r) {
        size_t row = row0 + wr + mi * 16 + rq + r;
        C[row * N + col] = (OutT)((acc[mi][ni][r] + bv) * premul);
      }
    }
  }
}

// ---------------- GEMM 256^2 8-phase retry (R2 body, correctness-verified) ----
// R2 regression root-caused to the XCD map: (wg&7)*(nwg/8)+wg/8 with col-major
// tile order gave each XCD ONE N-column x ALL M-tiles -> per-XCD re-fetch of
// the ENTIRE A matrix (264MB total vs 96MB) -> HBM/L2-bound at ~650 TF.
// Fix: chunked map — XCD k owns a contiguous block of 4 M-tiles x 8 N-tiles;
// all 256 blocks co-resident (1/CU); per-K-step XCD working set ~384KB << 4MB L2.
// Schedule (unchanged from R2, passed absmax there): 8 waves (2M x 4N), BK=64,
// half-tile ring of 4 slots/matrix (128KB LDS), stages p0:a_{2s+3} p1:b_{2s+3}
// p2:b_{2s+4} p3:a_{2s+4}, counted vmcnt(4) per step (0 only at s==NT-2),
// raw s_barrier + lgkmcnt(0) + sched_barrier(0) + setprio around MFMA clusters.
// LDS swizzle: 16B chunk c of row r holds global chunk c^(r&7) (write via
// pre-swizzled global source; read chunk (kh*4+quad)^(lr&7) -> 2-way max).
template<typename OutT, int K>
__global__ __launch_bounds__(512, 2) void gemm8_kernel(
    const bf16_t* __restrict__ A, const bf16_t* __restrict__ Wt,
    const float* __restrict__ bias, OutT* __restrict__ C,
    int M, int N, float premul)
{
  constexpr int NT = K / 64;
  __shared__ __align__(16) bf16_t AS[4 * 8192];
  __shared__ __align__(16) bf16_t BS[4 * 8192];
  int tid = threadIdx.x, lane = tid & 63, wave = tid >> 6;
  int wm = wave >> 2, wn = wave & 3;
  int lr = lane & 15, quad = lane >> 4, rq = quad * 4;
  int rsw = lr & 7;

  // chunked XCD map: XCD (wg&7) owns mtiles/8 consecutive M-tile rows x all N-tiles
  int wg = blockIdx.x;
  int ntiles = N >> 8;
  int mtpx = (M >> 8) >> 3;            // M-tiles per XCD
  int xcd = wg & 7, j = wg >> 3;
  int mt = xcd * mtpx + j / ntiles;
  int nt = j % ntiles;
  size_t row0 = (size_t)mt * 256;
  size_t col0 = (size_t)nt * 256;

  // staging source: per-thread row within a 64-row q-block + pre-swizzled chunk
  int srow = (wave << 3) + (lane >> 3);           // 0..63 ; (srow & 7) == lane>>3
  int scol = ((lane & 7) ^ (lane >> 3)) * 8;      // source chunk = dest ^ (row&7)
  const bf16_t* Abase = A  + (row0 + srow) * K + scol;
  const bf16_t* Bbase = Wt + (col0 + srow) * K + scol;

  auto stageA = [&](int jj) {
    int kt = jj >> 1, half = jj & 1, slot = jj & 3;
    const bf16_t* g = Abase + (size_t)(half * 128) * K + kt * 64;
    bf16_t* l = AS + slot * 8192 + wave * 512;
    load_lds16(g,                  l);
    load_lds16(g + (size_t)64 * K, l + 4096);
  };
  auto stageB = [&](int jj) {
    int kt = jj >> 1, half = jj & 1, slot = jj & 3;
    const bf16_t* g = Bbase + (size_t)(half * 128) * K + kt * 64;
    bf16_t* l = BS + slot * 8192 + wave * 512;
    load_lds16(g,                  l);
    load_lds16(g + (size_t)64 * K, l + 4096);
  };

  f32x4 acc[8][4] = {};
  bf16x8 aF[4][2], bF[2][2][2];   // bF[Nh][n][kh]

  // prologue: units a0,b0,a1,b1 (tile 0) + a2,b2 (tile 1 half 0)
  stageA(0); stageB(0); stageA(1); stageB(1); stageA(2); stageB(2);
  asm volatile("s_waitcnt vmcnt(4)" ::: "memory");   // tile 0 landed; a2,b2 in flight
  __builtin_amdgcn_s_barrier();

  for (int s = 0; s < NT; ++s) {
    const bf16_t* Asl = AS + ((2 * s + wm) & 3) * 8192;
    const bf16_t* Bsl = BS + ((2 * s + (wn >> 1)) & 3) * 8192;

    // ---- phase 0: quadrant (M0,N0); load A-M0 (8) + B-N0 (4); stage a_{2s+3}
    #pragma unroll
    for (int m = 0; m < 4; ++m)
      #pragma unroll
      for (int kh = 0; kh < 2; ++kh)
        aF[m][kh] = *(const bf16x8*)&Asl[(m * 16 + lr) * 64 + (((kh * 4 + quad) ^ rsw) * 8)];
    #pragma unroll
    for (int n = 0; n < 2; ++n)
      #pragma unroll
      for (int kh = 0; kh < 2; ++kh)
        bF[0][n][kh] = *(const bf16x8*)&Bsl[((wn & 1) * 64 + n * 16 + lr) * 64 + (((kh * 4 + quad) ^ rsw) * 8)];
    if (2 * s + 3 < 2 * NT) stageA(2 * s + 3);
    __builtin_amdgcn_s_barrier();
    asm volatile("s_waitcnt lgkmcnt(0)" ::: "memory");
    __builtin_amdgcn_sched_barrier(0);
    __builtin_amdgcn_s_setprio(1);
    #pragma unroll
    for (int m = 0; m < 4; ++m)
      #pragma unroll
      for (int n = 0; n < 2; ++n)
        #pragma unroll
        for (int kh = 0; kh < 2; ++kh)
          acc[m][n] = __builtin_amdgcn_mfma_f32_16x16x32_bf16(aF[m][kh], bF[0][n][kh], acc[m][n], 0, 0, 0);
    __builtin_amdgcn_s_setprio(0);
    __builtin_amdgcn_s_barrier();

    // ---- phase 1: quadrant (M0,N1); load B-N1 (4); stage b_{2s+3}
    #pragma unroll
    for (int n = 0; n < 2; ++n)
      #pragma unroll
      for (int kh = 0; kh < 2; ++kh)
        bF[1][n][kh] = *(const bf16x8*)&Bsl[((wn & 1) * 64 + 32 + n * 16 + lr) * 64 + (((kh * 4 + quad) ^ rsw) * 8)];
    if (2 * s + 3 < 2 * NT) stageB(2 * s + 3);
    __builtin_amdgcn_s_barrier();
    asm volatile("s_waitcnt lgkmcnt(0)" ::: "memory");
    __builtin_amdgcn_sched_barrier(0);
    __builtin_amdgcn_s_setprio(1);
    #pragma unroll
    for (int m = 0; m < 4; ++m)
      #pragma unroll
      for (int n = 0; n < 2; ++n)
        #pragma unroll
        for (int kh = 0; kh < 2; ++kh)
          acc[m][2 + n] = __builtin_amdgcn_mfma_f32_16x16x32_bf16(aF[m][kh], bF[1][n][kh], acc[m][2 + n], 0, 0, 0);
    __builtin_amdgcn_s_setprio(0);
    __builtin_amdgcn_s_barrier();

    // ---- phase 2: quadrant (M1,N0); load A-M1 (8); stage b_{2s+4}
    #pragma unroll
    for (int m = 0; m < 4; ++m)
      #pragma unroll
      for (int kh = 0; kh < 2; ++kh)
        aF[m][kh] = *(const bf16x8*)&Asl[(64 + m * 16 + lr) * 64 + (((kh * 4 + quad) ^ rsw) * 8)];
    if (2 * s + 4 < 2 * NT) stageB(2 * s + 4);
    __builtin_amdgcn_s_barrier();
    asm volatile("s_waitcnt lgkmcnt(0)" ::: "memory");
    __builtin_amdgcn_sched_barrier(0);
    __builtin_amdgcn_s_setprio(1);
    #pragma unroll
    for (int m = 0; m < 4; ++m)
      #pragma unroll
      for (int n = 0; n < 2; ++n)
        #pragma unroll
        for (int kh = 0; kh < 2; ++kh)
          acc[4 + m][n] = __builtin_amdgcn_mfma_f32_16x16x32_bf16(aF[m][kh], bF[0][n][kh], acc[4 + m][n], 0, 0, 0);
    __builtin_amdgcn_s_setprio(0);
    __builtin_amdgcn_s_barrier();

    // ---- phase 3: quadrant (M1,N1); no loads; stage a_{2s+4}
    if (2 * s + 4 < 2 * NT) stageA(2 * s + 4);
    __builtin_amdgcn_s_barrier();
    __builtin_amdgcn_s_setprio(1);
    #pragma unroll
    for (int m = 0; m < 4; ++m)
      #pragma unroll
      for (int n = 0; n < 2; ++n)
        #pragma unroll
        for (int kh = 0; kh < 2; ++kh)
          acc[4 + m][2 + n] = __builtin_amdgcn_mfma_f32_16x16x32_bf16(aF[m][kh], bF[1][n][kh], acc[4 + m][2 + n], 0, 0, 0);
    __builtin_amdgcn_s_setprio(0);
    // step-boundary wait: tile s+1 (units <= 2s+3) landed; 2 newest units may fly
    if (s < NT - 2)       asm volatile("s_waitcnt vmcnt(4)" ::: "memory");
    else if (s == NT - 2) asm volatile("s_waitcnt vmcnt(0)" ::: "memory");
    __builtin_amdgcn_s_barrier();
  }

  // epilogue: row = row0 + wm*128 + mh*64 + m*16 + rq + r ; col = col0 + wn*64 + nh*32 + n*16 + lr
  #pragma unroll
  for (int mh = 0; mh < 2; ++mh)
    #pragma unroll
    for (int nh = 0; nh < 2; ++nh)
      #pragma unroll
      for (int n = 0; n < 2; ++n) {
        int col = (int)col0 + wn * 64 + nh * 32 + n * 16 + lr;
        float bv = bias[col];
        #pragma unroll
        for (int m = 0; m < 4; ++m)
          #pragma unroll
          for (int r = 0; r < 4; ++r) {
            size_t row = row0 + wm * 128 + mh * 64 + m * 16 + rq + r;
            C[row * N + col] = (OutT)((acc[mh * 4 + m][nh * 2 + n][r] + bv) * premul);
          }
      }
}

// fused uk+uv GEMM (A=lat, K=512). blockIdx.y<16 -> keys; y>=16 -> uv with
// transposing epilogue writing vt[bh][d][s] directly (R6-verified).
__global__ __launch_bounds__(256, 2) void gemm_kv_kernel(
    const bf16_t* __restrict__ A, const bf16_t* __restrict__ WtK,
    const bf16_t* __restrict__ WtV, const float* __restrict__ biasK,
    const float* __restrict__ biasV, bf16_t* __restrict__ keysO,
    bf16_t* __restrict__ vtO, int M)
{
  const int K = D_LATENT;
  __shared__ __align__(16) bf16_t As[128 * 32];
  __shared__ __align__(16) bf16_t Bs[128 * 32];
  __shared__ __align__(16) bf16_t E[64 * 136];
  int tid = threadIdx.x;
  int lane = tid & 63, wave = tid >> 6;
  int wr = (wave >> 1) * 64, wc = (wave & 1) * 64;
  int yb = blockIdx.y;
  bool isv = yb >= 16;
  const bf16_t* Wt = isv ? WtV : WtK;
  const float* bias = isv ? biasV : biasK;
  size_t row0 = (size_t)blockIdx.x * 128, col0 = (size_t)(isv ? yb - 16 : yb) * 128;
  int lr = lane & 15, quad = lane >> 4, rq = quad * 4;

  f32x4 acc[4][4] = {};

  int srow = wave * 32 + (lane >> 2);
  int scol = ((lane & 3) ^ ((lane >> 3) & 3)) * 8;
  const bf16_t* Ag = A  + (row0 + srow) * K + scol;
  const bf16_t* Bg = Wt + (col0 + srow) * K + scol;
  bf16_t* Asw = As + wave * 1024;
  bf16_t* Bsw = Bs + wave * 1024;

  int rchunk = (quad ^ ((lr >> 1) & 3)) * 8;

  for (int k0 = 0; k0 < K; k0 += 32) {
    __syncthreads();
    load_lds16(Ag,          Asw);
    load_lds16(Ag + 16 * K, Asw + 512);
    load_lds16(Bg,          Bsw);
    load_lds16(Bg + 16 * K, Bsw + 512);
    Ag += 32; Bg += 32;
    __syncthreads();

    bf16x8 af[4], bfr[4];
    #pragma unroll
    for (int mi = 0; mi < 4; ++mi)
      af[mi] = *(const bf16x8*)&As[(wr + mi * 16 + lr) * 32 + rchunk];
    #pragma unroll
    for (int ni = 0; ni < 4; ++ni)
      bfr[ni] = *(const bf16x8*)&Bs[(wc + ni * 16 + lr) * 32 + rchunk];
    #pragma unroll
    for (int mi = 0; mi < 4; ++mi)
      #pragma unroll
      for (int ni = 0; ni < 4; ++ni)
        acc[mi][ni] = __builtin_amdgcn_mfma_f32_16x16x32_bf16(af[mi], bfr[ni], acc[mi][ni], 0, 0, 0);
  }

  if (!isv) {
    #pragma unroll
    for (int ni = 0; ni < 4; ++ni) {
      int col = (int)col0 + wc + ni * 16 + lr;
      float bv = bias[col];
      #pragma unroll
      for (int mi = 0; mi < 4; ++mi) {
        #pragma unroll
        for (int r = 0; r < 4; ++r) {
          size_t row = row0 + wr + mi * 16 + rq + r;
          keysO[row * D_MODEL + col] = (bf16_t)(acc[mi][ni][r] + bv);
        }
      }
    }
  } else {
    int b = (int)(row0 >> 11);
    int s0 = (int)(row0 & 2047);
    int h = yb - 16;
    bf16_t* vtb = vtO + (size_t)(b * NUM_HEADS + h) * D_HEAD * SEQ;
    #pragma unroll
    for (int h2 = 0; h2 < 2; ++h2) {
      __syncthreads();
      if ((wave & 1) == h2) {
        #pragma unroll
        for (int ni = 0; ni < 4; ++ni) {
          int dh = ni * 16 + lr;
          float bv = bias[(int)col0 + h2 * 64 + dh];
          #pragma unroll
          for (int mi = 0; mi < 4; ++mi) {
            #pragma unroll
            for (int r = 0; r < 4; ++r) {
              int s = wr + mi * 16 + rq + r;
              E[dh * 136 + s] = (bf16_t)(acc[mi][ni][r] + bv);
            }
          }
        }
      }
      __syncthreads();
      for (int t = tid; t < 1024; t += 256) {
        int d = t >> 4, ch = t & 15;
        bf16x8 v = *(const bf16x8*)&E[d * 136 + ch * 8];
        *(bf16x8*)&vtb[(size_t)(h2 * 64 + d) * SEQ + s0 + ch * 8] = v;
      }
    }
  }
}

// ---------------- flash attention (R7/R8-verified, 198.5us; frozen) ----------------
__global__ __launch_bounds__(256, 2) void attention_kernel(
    const bf16_t* __restrict__ q, const bf16_t* __restrict__ keys,
    const bf16_t* __restrict__ vt, bf16_t* __restrict__ ctx)
{
  __shared__ __align__(16) bf16_t KS[2][64 * 128];   // 32KB  [key][d] swizzled
  __shared__ __align__(16) bf16_t VS[2][128 * 64];   // 32KB  [d][key] swizzled
  __shared__ __align__(16) bf16_t PS[128 * 64];      // 16KB  [q][key] swizzled
  int wg = blockIdx.x;
  int qt = (wg >> 3) & 15;
  int bh = (wg & 7) | ((wg >> 7) << 3);
  int b = bh >> 4, h = bh & 15;
  int tid = threadIdx.x, lane = tid & 63, wave = tid >> 6;
  int lr = lane & 15, quad = lane >> 4, kq = quad * 8, rq = quad * 4;
  int l7 = lr & 7;

  const bf16_t* qg = q    + (size_t)(b * SEQ + qt * 128) * D_MODEL + h * D_HEAD;
  const bf16_t* kg = keys + (size_t)b * SEQ * D_MODEL + h * D_HEAD;
  const bf16_t* vg = vt   + (size_t)bh * D_HEAD * SEQ;

  bf16x8 qf[2][4];
  #pragma unroll
  for (int mi = 0; mi < 2; ++mi)
    #pragma unroll
    for (int ks = 0; ks < 4; ++ks)
      qf[mi][ks] = *(const bf16x8*)&qg[(size_t)(wave*32 + mi*16 + lr) * D_MODEL + ks*32 + kq];

  int koff[4], voff2[2], poff2[2], pwaddr[4];
  #pragma unroll
  for (int ks = 0; ks < 4; ++ks)
    koff[ks] = lr * 128 + (((ks*4 + quad) ^ l7) * 8);
  #pragma unroll
  for (int ks2 = 0; ks2 < 2; ++ks2) {
    voff2[ks2] = lr * 64 + (((ks2*4 + quad) ^ l7) * 8);
    poff2[ks2] = (wave*32 + lr) * 64 + (((ks2*4 + quad) ^ l7) * 8);
  }
  #pragma unroll
  for (int ni = 0; ni < 4; ++ni)
    pwaddr[ni] = (wave*32 + lr) * 64 + (((ni*2 + (quad>>1)) ^ l7) * 8) + (quad&1)*4;

  bf16x8 kreg[4], vreg[4];
  const bf16_t* kp4[4];
  const bf16_t* vp4[4];
  int kdo[4], vdo[4];
  #pragma unroll
  for (int i = 0; i < 4; ++i) {
    int c = tid + i * 256;
    int r = c >> 4, kc = c & 15;
    kp4[i] = kg + (size_t)r * D_MODEL + kc * 8;
    kdo[i] = r * 128 + ((kc ^ (r & 7)) * 8);
    int d = c >> 3, vc = c & 7;
    vp4[i] = vg + (size_t)d * SEQ + vc * 8;
    vdo[i] = d * 64 + ((vc ^ (d & 7)) * 8);
  }

  #pragma unroll
  for (int i = 0; i < 4; ++i) {
    kreg[i] = *(const bf16x8*)kp4[i];
    vreg[i] = *(const bf16x8*)vp4[i];
  }
  #pragma unroll
  for (int i = 0; i < 4; ++i) {
    *(bf16x8*)&KS[0][kdo[i]] = kreg[i];
    *(bf16x8*)&VS[0][vdo[i]] = vreg[i];
  }
  #pragma unroll
  for (int i = 0; i < 4; ++i) {
    kp4[i] += 64 * D_MODEL;
    vp4[i] += 64;
    kreg[i] = *(const bf16x8*)kp4[i];
    vreg[i] = *(const bf16x8*)vp4[i];
  }

  f32x4 accO[2][8] = {};
  float m2[2]   = {-1e30f, -1e30f};
  float lsum[2] = {0.f, 0.f};
  const f32x4 z4 = {0.f, 0.f, 0.f, 0.f};

  __syncthreads();

  auto body = [&](int p, int kt) {
    f32x4 sc[2][4];
    {
      bf16x8 kf[4];
      #pragma unroll
      for (int ni = 0; ni < 4; ++ni)
        kf[ni] = *(const bf16x8*)&KS[p][koff[0] + ni*2048];
      __builtin_amdgcn_s_setprio(1);
      #pragma unroll
      for (int mi = 0; mi < 2; ++mi)
        #pragma unroll
        for (int ni = 0; ni < 4; ++ni)
          sc[mi][ni] = __builtin_amdgcn_mfma_f32_16x16x32_bf16(kf[ni], qf[mi][0], z4, 0, 0, 0);
      __builtin_amdgcn_s_setprio(0);
    }
    #pragma unroll
    for (int ks = 1; ks < 4; ++ks) {
      bf16x8 kf[4];
      #pragma unroll
      for (int ni = 0; ni < 4; ++ni)
        kf[ni] = *(const bf16x8*)&KS[p][koff[ks] + ni*2048];
      __builtin_amdgcn_s_setprio(1);
      #pragma unroll
      for (int mi = 0; mi < 2; ++mi)
        #pragma unroll
        for (int ni = 0; ni < 4; ++ni)
          sc[mi][ni] = __builtin_amdgcn_mfma_f32_16x16x32_bf16(kf[ni], qf[mi][ks], sc[mi][ni], 0, 0, 0);
      __builtin_amdgcn_s_setprio(0);
    }

    if (kt + 1 < SEQ/64) {
      #pragma unroll
      for (int i = 0; i < 4; ++i) {
        *(bf16x8*)&KS[p ^ 1][kdo[i]] = kreg[i];
        *(bf16x8*)&VS[p ^ 1][vdo[i]] = vreg[i];
      }
    }
    if (kt + 2 < SEQ/64) {
      #pragma unroll
      for (int i = 0; i < 4; ++i) {
        kp4[i] += 64 * D_MODEL;
        vp4[i] += 64;
        kreg[i] = *(const bf16x8*)kp4[i];
        vreg[i] = *(const bf16x8*)vp4[i];
      }
    }

    #pragma unroll
    for (int mi = 0; mi < 2; ++mi) {
      float rm = sc[mi][0][0];
      #pragma unroll
      for (int ni = 0; ni < 4; ++ni)
        #pragma unroll
        for (int r = 0; r < 4; ++r) rm = fmaxf(rm, sc[mi][ni][r]);
      rm = fmaxf(rm, __shfl_xor(rm, 16, 64));
      rm = fmaxf(rm, __shfl_xor(rm, 32, 64));

      if (!__all(rm - m2[mi] <= 8.0f)) {
        float mnew  = fmaxf(m2[mi], rm);
        float alpha = exp2f(m2[mi] - mnew);
        m2[mi] = mnew;
        lsum[mi] *= alpha;
        float ar[4];
        #pragma unroll
        for (int r = 0; r < 4; ++r) ar[r] = __shfl(alpha, rq + r, 16);
        #pragma unroll
        for (int nd = 0; nd < 8; ++nd)
          #pragma unroll
          for (int r = 0; r < 4; ++r) accO[mi][nd][r] *= ar[r];
      }

      float rs = 0.f;
      #pragma unroll
      for (int ni = 0; ni < 4; ++ni) {
        float p0 = exp2f(sc[mi][ni][0] - m2[mi]);
        float p1 = exp2f(sc[mi][ni][1] - m2[mi]);
        float p2 = exp2f(sc[mi][ni][2] - m2[mi]);
        float p3 = exp2f(sc[mi][ni][3] - m2[mi]);
        rs += (p0 + p1) + (p2 + p3);
        bf16x4 pk = { (bf16_t)p0, (bf16_t)p1, (bf16_t)p2, (bf16_t)p3 };
        if (mi == 0) *(bf16x4*)&PS[pwaddr[ni]]        = pk;
        else         *(bf16x4*)&PS[pwaddr[ni] + 1024] = pk;
      }
      rs += __shfl_xor(rs, 16, 64);
      rs += __shfl_xor(rs, 32, 64);
      lsum[mi] += rs;
    }

    #pragma unroll
    for (int ks2 = 0; ks2 < 2; ++ks2) {
      bf16x8 pf[2], vf[8];
      #pragma unroll
      for (int mi = 0; mi < 2; ++mi)
        pf[mi] = *(const bf16x8*)&PS[poff2[ks2] + mi*1024];
      #pragma unroll
      for (int nd = 0; nd < 8; ++nd)
        vf[nd] = *(const bf16x8*)&VS[p][voff2[ks2] + nd*1024];
      __builtin_amdgcn_s_setprio(1);
      #pragma unroll
      for (int mi = 0; mi < 2; ++mi)
        #pragma unroll
        for (int nd = 0; nd < 8; ++nd)
          accO[mi][nd] = __builtin_amdgcn_mfma_f32_16x16x32_bf16(pf[mi], vf[nd], accO[mi][nd], 0, 0, 0);
      __builtin_amdgcn_s_setprio(0);
    }

    __syncthreads();
  };

  for (int kt = 0; kt < SEQ/64; kt += 2) {
    body(0, kt);
    body(1, kt + 1);
  }

  bf16_t* og = ctx + (size_t)(b * SEQ + qt * 128) * D_MODEL + h * D_HEAD;
  #pragma unroll
  for (int mi = 0; mi < 2; ++mi) {
    float inv[4];
    #pragma unroll
    for (int r = 0; r < 4; ++r) inv[r] = 1.0f / __shfl(lsum[mi], rq + r, 16);
    #pragma unroll
    for (int r = 0; r < 4; ++r) {
      int row = wave*32 + mi*16 + rq + r;
      #pragma unroll
      for (int nd = 0; nd < 8; ++nd)
        og[(size_t)row * D_MODEL + nd*16 + lr] = (bf16_t)(accO[mi][nd][r] * inv[r]);
    }
  }
}

extern "C" void kernel_launch(void* const* d_in, const int* in_sizes, int n_in,
                              void* d_out, int out_size, void* d_ws, size_t ws_size,
                              hipStream_t stream) {
  const float* x      = (const float*)d_in[0];
  const float* W_down = (const float*)d_in[1];
  const float* b_down = (const float*)d_in[2];
  const float* W_uk   = (const float*)d_in[3];
  const float* b_uk   = (const float*)d_in[4];
  const float* W_uv   = (const float*)d_in[5];
  const float* b_uv   = (const float*)d_in[6];
  const float* W_q    = (const float*)d_in[7];
  const float* b_q    = (const float*)d_in[8];
  const float* W_o    = (const float*)d_in[9];
  const float* b_o    = (const float*)d_in[10];
  float* out = (float*)d_out;

  char* ws = (char*)d_ws;
  bf16_t* xb      = (bf16_t*)ws;  ws += (size_t)MTOK*D_MODEL*2;
  bf16_t* Wt_down = (bf16_t*)ws;  ws += (size_t)D_LATENT*D_MODEL*2;
  bf16_t* Wt_uk   = (bf16_t*)ws;  ws += (size_t)D_MODEL*D_LATENT*2;
  bf16_t* Wt_uv   = (bf16_t*)ws;  ws += (size_t)D_MODEL*D_LATENT*2;
  bf16_t* Wt_q    = (bf16_t*)ws;  ws += (size_t)D_MODEL*D_MODEL*2;
  bf16_t* Wt_o    = (bf16_t*)ws;  ws += (size_t)D_MODEL*D_MODEL*2;
  bf16_t* lat     = (bf16_t*)ws;  ws += (size_t)MTOK*D_LATENT*2;
  bf16_t* keys    = (bf16_t*)ws;  ws += (size_t)MTOK*D_MODEL*2;
  bf16_t* vals    = (bf16_t*)ws;  ws += (size_t)MTOK*D_MODEL*2;  // ctx only
  bf16_t* qm      = (bf16_t*)ws;  ws += (size_t)MTOK*D_MODEL*2;
  bf16_t* vtm     = (bf16_t*)ws;  ws += (size_t)MTOK*D_MODEL*2;
  bf16_t* ctx     = vals;

  const float cs = 0.0883883476483184f * 1.44269504089f;  // 1/sqrt(128) * log2(e)

  convert_f32_bf16_kernel<<<(MTOK*D_MODEL/4 + 255)/256, 256, 0, stream>>>(x, xb, MTOK*D_MODEL/4);

  transpose_w_all<<<dim3(32, 32, 5), 256, 0, stream>>>(
      W_down, W_uk, W_uv, W_q, W_o, Wt_down, Wt_uk, Wt_uv, Wt_q, Wt_o);

  // down-proj (N=512): 128^2 kernel
  gemm_bt_kernel<bf16_t><<<dim3(MTOK/128, D_LATENT/128), 256, 0, stream>>>(
      xb, Wt_down, b_down, lat, MTOK, D_LATENT, D_MODEL, 1.0f);

  // q-proj: 256^2 8-phase with chunked XCD map (grid 256 wg = 1/CU)
  gemm8_kernel<bf16_t, 2048><<<(MTOK/256)*(D_MODEL/256), 512, 0, stream>>>(
      xb, Wt_q, b_q, qm, MTOK, D_MODEL, cs);

  // fused uk + uv (K=512); uv half writes vt layout directly
  gemm_kv_kernel<<<dim3(MTOK/128, 32), 256, 0, stream>>>(
      lat, Wt_uk, Wt_uv, b_uk, b_uv, keys, vtm, MTOK);

  attention_kernel<<<1024, 256, 0, stream>>>(qm, keys, vtm, ctx);

  // o-proj: 256^2 8-phase with chunked XCD map
  gemm8_kernel<float, 2048><<<(MTOK/256)*(D_MODEL/256), 512, 0, stream>>>(
      ctx, Wt_o, b_o, out, MTOK, D_MODEL, 1.0f);
}